// Round 7
// baseline (5652.233 us; speedup 1.0000x reference)
//
#include <hip/hip_runtime.h>
#include <hip/hip_bf16.h>
#include <cstdint>

// Problem constants
constexpr int kT = 128;    // sequence length
constexpr int kB = 256;    // batch
constexpr int kE = 512;    // embed dim
constexpr int kH = 1024;   // hidden
constexpr int kV = 348;    // vocab
constexpr int kNG = 3072;  // 3*H gate width
constexpr int NB = 400;    // 384 layer blocks + 16 E blocks; 2 blocks/CU -> all resident

constexpr float kScale = 32.f;         // fp8 storage scale (avoids e4m3 subnormal floor)
constexpr float kInvSS = 1.f / 1024.f; // 1/(kScale*kScale) applied to accumulators

typedef float f4v __attribute__((ext_vector_type(4)));   // MFMA accumulator
typedef unsigned short u16;
typedef unsigned char u8;

// float -> fp8 e4m3 (OCP) via HW packed convert; low byte of the pair
__device__ __forceinline__ u8 f2e4m3(float x) {
  int p = __builtin_amdgcn_cvt_pk_fp8_f32(x, x, 0, false);
  return (u8)(p & 0xff);
}

// device-coherent (cross-XCD) accessors: bypass L1/L2, hit MALL coherent point
__device__ __forceinline__ uint64_t ldv_u64(const void* p) {
  return __hip_atomic_load((const uint64_t*)p, __ATOMIC_RELAXED, __HIP_MEMORY_SCOPE_AGENT);
}
__device__ __forceinline__ void stv_u8(u8* p, u8 v) {
  __hip_atomic_store(p, v, __ATOMIC_RELAXED, __HIP_MEMORY_SCOPE_AGENT);
}

// gate-major n = gate*H + j  ->  interleaved col = 48*(j/16) + 16*gate + (j%16)
__device__ __forceinline__ int permn(int n) {
  int gate = n >> 10, j = n & 1023;
  return ((j >> 4) * 48) + gate * 16 + (j & 15);
}

struct Params {
  const int* target; const int* bosp; const float* b_out;
  const u8 *w1i, *w1h, *w2i, *w2h, *w3i, *w3h, *wout, *embb;  // fp8 x32
  const float *bi1, *bh1, *bi2, *bh2, *bi3, *bh3;
  float *h1f, *h2f, *h3f;       // [2][B][H] fp32 state (block-local, cached)
  u8    *h1b, *h2b, *h3b;       // [2][B][H] fp8 x32 state (cross-block, sc1)
  float *lp;                    // [B] output accumulator (= d_out)
  unsigned *acnt; unsigned *gflag;
};

union SMem {
  struct { u8 A[64 * 144]; u8 B[96 * 144]; } mm;  // 22.5 KB: 2 blocks/CU co-resident
  float logits[16 * 400];
};

// ---- grid barrier: relaxed flag ops only, no cache-maintenance fences ----
__device__ __forceinline__ void gbar(unsigned* acnt, unsigned* gflag, unsigned s) {
  asm volatile("s_waitcnt vmcnt(0)" ::: "memory");
  __syncthreads();
  if (threadIdx.x == 0) {
    const unsigned g = blockIdx.x & 63u;
    __hip_atomic_fetch_add(&acnt[g * 16], 1u, __ATOMIC_RELAXED, __HIP_MEMORY_SCOPE_AGENT);
    if (blockIdx.x == 0) {
      for (;;) {
        unsigned sum = 0;
#pragma unroll
        for (int i = 0; i < 64; ++i)
          sum += __hip_atomic_load(&acnt[i * 16], __ATOMIC_RELAXED, __HIP_MEMORY_SCOPE_AGENT);
        if (sum >= (unsigned)NB * (s + 1u)) break;
        __builtin_amdgcn_s_sleep(4);
      }
#pragma unroll
      for (int i = 0; i < 64; ++i)
        __hip_atomic_store(&gflag[i * 16], s + 1u, __ATOMIC_RELAXED, __HIP_MEMORY_SCOPE_AGENT);
    } else {
      while (__hip_atomic_load(&gflag[g * 16], __ATOMIC_RELAXED, __HIP_MEMORY_SCOPE_AGENT) <= s)
        __builtin_amdgcn_s_sleep(8);
    }
    asm volatile("" ::: "memory");
  }
  __syncthreads();
}

// ---------------- one matmul phase: acc{R,Z,N} += A(64xK) @ W(96xK)^T, fp8, BK=128 ----------------
// 1-deep register prefetch. EMB: A gathered from fp8 embedding (cached); else sc1 h-state.
template<int K, bool EMB>
__device__ __forceinline__ void mm_phase(SMem& sm, const u8* __restrict__ Asrc,
    const u8* __restrict__ W, int b0, int n0,
    f4v* aR, f4v* aZ, f4v* aN,
    const int* __restrict__ target, int bos, int u)
{
  const int t = threadIdx.x, lane = t & 63, wv = t >> 6;
  const int wm = wv >> 1, wg = wv & 1, li = lane & 15, q = lane >> 4;
  uint64_t ra[2][2];
  uint4 rb[3];

  auto stage = [&](int k0) {
#pragma unroll
    for (int p = 0; p < 2; ++p) {                 // A: 64 rows x 128B, 16B chunks
      int id = p * 256 + t, r = id >> 3, c = id & 7;
      if (EMB) {
        int tok = (u == 0) ? bos : target[(b0 + r) * kT + (u - 1)];
        uint4 v = *(const uint4*)&Asrc[(size_t)tok * K + k0 + c * 16];
        ra[p][0] = ((uint64_t)v.y << 32) | v.x;
        ra[p][1] = ((uint64_t)v.w << 32) | v.z;
      } else {
        const u8* src = Asrc + (size_t)(b0 + r) * kH + k0 + c * 16;
        ra[p][0] = ldv_u64(src); ra[p][1] = ldv_u64(src + 8);
      }
    }
#pragma unroll
    for (int p = 0; p < 3; ++p) {                 // B: 96 weight rows (cached, L2-resident)
      int id = p * 256 + t, r = id >> 3, c = id & 7;
      rb[p] = *(const uint4*)&W[(size_t)(n0 + r) * K + k0 + c * 16];
    }
  };

  stage(0);
  for (int it = 0; it < K / 128; ++it) {
    __syncthreads();
#pragma unroll
    for (int p = 0; p < 2; ++p) {
      int id = p * 256 + t, r = id >> 3, c = id & 7;
      *(uint64_t*)&sm.mm.A[r * 144 + c * 16] = ra[p][0];
      *(uint64_t*)&sm.mm.A[r * 144 + c * 16 + 8] = ra[p][1];
    }
#pragma unroll
    for (int p = 0; p < 3; ++p) {
      int id = p * 256 + t, r = id >> 3, c = id & 7;
      *(uint4*)&sm.mm.B[r * 144 + c * 16] = rb[p];
    }
    __syncthreads();
    if (it + 1 < K / 128) stage((it + 1) * 128);  // prefetch overlaps MFMAs below
#pragma unroll
    for (int kk = 0; kk < 128; kk += 32) {
      int lk = kk + q * 8;
      long a[2], bb[3];
#pragma unroll
      for (int m2 = 0; m2 < 2; ++m2)
        a[m2] = *(const long*)&sm.mm.A[(32 * wm + 16 * m2 + li) * 144 + lk];
#pragma unroll
      for (int g = 0; g < 3; ++g)
        bb[g] = *(const long*)&sm.mm.B[(48 * wg + 16 * g + li) * 144 + lk];
#pragma unroll
      for (int m2 = 0; m2 < 2; ++m2) {
        aR[m2] = __builtin_amdgcn_mfma_f32_16x16x32_fp8_fp8(a[m2], bb[0], aR[m2], 0, 0, 0);
        aZ[m2] = __builtin_amdgcn_mfma_f32_16x16x32_fp8_fp8(a[m2], bb[1], aZ[m2], 0, 0, 0);
        aN[m2] = __builtin_amdgcn_mfma_f32_16x16x32_fp8_fp8(a[m2], bb[2], aN[m2], 0, 0, 0);
      }
    }
  }
}

// ---------------- merged layer stage: gi + gh + GRU update, tile 64b x 32j ----------------
template<int K1, bool L1>
__device__ void do_L(SMem& sm, const u8* __restrict__ xsrc,
                     const u8* __restrict__ hbPrev, const float* __restrict__ hfPrev,
                     const u8* __restrict__ Wih, const u8* __restrict__ Whh,
                     const float* __restrict__ biP, const float* __restrict__ bhP,
                     float* __restrict__ hfOut, u8* __restrict__ hbOut,
                     const int* __restrict__ target, int bos, int u, int mt, int jt)
{
  const int b0 = mt * 64, j0 = jt * 32, n0 = jt * 96;
  f4v aR[2], aZ[2], aNi[2], aNh[2];
#pragma unroll
  for (int i = 0; i < 2; ++i) {
    aR[i] = f4v{0.f,0.f,0.f,0.f}; aZ[i] = f4v{0.f,0.f,0.f,0.f};
    aNi[i] = f4v{0.f,0.f,0.f,0.f}; aNh[i] = f4v{0.f,0.f,0.f,0.f};
  }
  mm_phase<K1, L1>(sm, xsrc, Wih, b0, n0, aR, aZ, aNi, target, bos, u);      // gi
  mm_phase<kH, false>(sm, hbPrev, Whh, b0, n0, aR, aZ, aNh, target, bos, u); // gh

  const int t = threadIdx.x, lane = t & 63, wv = t >> 6;
  const int wm = wv >> 1, wg = wv & 1, li = lane & 15, q = lane >> 4;
  const int j = j0 + 16 * wg + li;
  const int cr = n0 + 48 * wg + li;
  const float bR = biP[cr] + bhP[cr];
  const float bZ = biP[cr + 16] + bhP[cr + 16];
  const float biN = biP[cr + 32], bhN = bhP[cr + 32];
  float hold[2][4];
#pragma unroll
  for (int m2 = 0; m2 < 2; ++m2)
#pragma unroll
    for (int r = 0; r < 4; ++r) {
      int b = b0 + 32 * wm + 16 * m2 + 4 * q + r;
      hold[m2][r] = hfPrev[(size_t)b * kH + j];  // block-local, cached
    }
#pragma unroll
  for (int m2 = 0; m2 < 2; ++m2)
#pragma unroll
    for (int r = 0; r < 4; ++r) {
      int b = b0 + 32 * wm + 16 * m2 + 4 * q + r;
      float rg = 1.f / (1.f + __expf(-(aR[m2][r] * kInvSS + bR)));
      float zg = 1.f / (1.f + __expf(-(aZ[m2][r] * kInvSS + bZ)));
      float np = (aNi[m2][r] * kInvSS + biN) + rg * (aNh[m2][r] * kInvSS + bhN);
      float nh = 2.f / (1.f + __expf(-2.f * np)) - 1.f;   // tanh
      float hnew = (1.f - zg) * nh + zg * hold[m2][r];
      hfOut[(size_t)b * kH + j] = hnew;                   // local fp32, cached
      stv_u8(&hbOut[(size_t)b * kH + j], f2e4m3(hnew * kScale));  // cross-block fp8, sc1
    }
}

// ---------------- E stage: logits + log_softmax + gather (16 rows/block) ----------------
__device__ void do_E(SMem& sm, const u8* __restrict__ h3b, const u8* __restrict__ wo,
                     const float* __restrict__ b_out, const int* __restrict__ target,
                     float* __restrict__ lp, int u, int tile)
{
  const int b0 = tile * 16;
  const int t = threadIdx.x, lane = t & 63, wv = t >> 6;
  const int li = lane & 15, q = lane >> 4;
  f4v acc[6];
#pragma unroll
  for (int f = 0; f < 6; ++f) acc[f] = f4v{0.f, 0.f, 0.f, 0.f};

  const u8* ap = h3b + (size_t)(b0 + li) * kH + q * 8;
  uint64_t aCur = ldv_u64(ap);
  uint64_t bCur[6], bNx[6];
#pragma unroll
  for (int f = 0; f < 6; ++f)
    bCur[f] = *(const uint64_t*)&wo[(size_t)(96 * wv + 16 * f + li) * kH + q * 8];
  for (int k0 = 0; k0 < kH; k0 += 32) {
    uint64_t aNx = 0;
    if (k0 + 32 < kH) {
      aNx = ldv_u64(ap + k0 + 32);
#pragma unroll
      for (int f = 0; f < 6; ++f)
        bNx[f] = *(const uint64_t*)&wo[(size_t)(96 * wv + 16 * f + li) * kH + k0 + 32 + q * 8];
    }
#pragma unroll
    for (int f = 0; f < 6; ++f)
      acc[f] = __builtin_amdgcn_mfma_f32_16x16x32_fp8_fp8((long)aCur, (long)bCur[f], acc[f], 0, 0, 0);
    aCur = aNx;
#pragma unroll
    for (int f = 0; f < 6; ++f) bCur[f] = bNx[f];
  }
#pragma unroll
  for (int f = 0; f < 6; ++f) {
    int n = 96 * wv + 16 * f + li;
    if (n < kV) {
      float bo = b_out[n];
#pragma unroll
      for (int r = 0; r < 4; ++r)
        sm.logits[(4 * q + r) * 400 + n] = acc[f][r] * kInvSS + bo;
    }
  }
  __syncthreads();
  int m = 4 * wv + q;
  int b = b0 + m;
  float mx = -1e30f;
  for (int cc = li; cc < kV; cc += 16) mx = fmaxf(mx, sm.logits[m * 400 + cc]);
#pragma unroll
  for (int d = 1; d < 16; d <<= 1) mx = fmaxf(mx, __shfl_xor(mx, d, 16));
  float se = 0.f;
  for (int cc = li; cc < kV; cc += 16) se += __expf(sm.logits[m * 400 + cc] - mx);
#pragma unroll
  for (int d = 1; d < 16; d <<= 1) se += __shfl_xor(se, d, 16);
  int tgt = target[b * kT + u];
  float logp = sm.logits[m * 400 + tgt] - mx - __logf(se);
  if (li == 0) lp[b] += logp;
}

// ---------------- main persistent kernel (2 blocks/CU) ----------------
__global__ __launch_bounds__(256, 2) void rnn_main(Params P)
{
  __shared__ SMem sm;
  const int bid = blockIdx.x;
  const int bos = P.bosp[0];
  const size_t HS = (size_t)kB * kH;

  // within layer: local in [0,128): jt = local&31, mt = local>>5.
  // same-jt blocks sit 32 bids apart -> same XCD under bid%8 round-robin (weight L2 reuse).
  const int local = bid & 127;
  const int mt = local >> 5;
  const int jt = local & 31;

  for (int s = 0; s < kT + 3; ++s) {
    if (bid < 128) {                       // layer 1, u = s
      int u = s;
      if (u < kT)
        do_L<kE, true>(sm, P.embb,
                       P.h1b + (size_t)((u - 1) & 1) * HS, P.h1f + (size_t)((u - 1) & 1) * HS,
                       P.w1i, P.w1h, P.bi1, P.bh1,
                       P.h1f + (size_t)(u & 1) * HS, P.h1b + (size_t)(u & 1) * HS,
                       P.target, bos, u, mt, jt);
    } else if (bid < 256) {                // layer 2, u = s-1
      int u = s - 1;
      if (u >= 0 && u < kT)
        do_L<kH, false>(sm, P.h1b + (size_t)(u & 1) * HS,
                        P.h2b + (size_t)((u - 1) & 1) * HS, P.h2f + (size_t)((u - 1) & 1) * HS,
                        P.w2i, P.w2h, P.bi2, P.bh2,
                        P.h2f + (size_t)(u & 1) * HS, P.h2b + (size_t)(u & 1) * HS,
                        P.target, bos, u, mt, jt);
    } else if (bid < 384) {                // layer 3, u = s-2
      int u = s - 2;
      if (u >= 0 && u < kT)
        do_L<kH, false>(sm, P.h2b + (size_t)(u & 1) * HS,
                        P.h3b + (size_t)((u - 1) & 1) * HS, P.h3f + (size_t)((u - 1) & 1) * HS,
                        P.w3i, P.w3h, P.bi3, P.bh3,
                        P.h3f + (size_t)(u & 1) * HS, P.h3b + (size_t)(u & 1) * HS,
                        P.target, bos, u, mt, jt);
    } else {                               // E, u = s-3
      int u = s - 3;
      if (u >= 0 && u < kT)
        do_E(sm, P.h3b + (size_t)(u & 1) * HS, P.wout, P.b_out, P.target, P.lp, u, bid - 384);
    }
    gbar(P.acnt, P.gflag, (unsigned)s);
  }
}

// ---------------- conversion / init kernels (fp8 x32) ----------------
__global__ void k_conv_w(const float* __restrict__ w, u8* __restrict__ wp, int K, int logK) {
  int idx = blockIdx.x * 256 + threadIdx.x;
  if (idx >= kNG * K) return;
  int n = idx >> logK, k = idx & (K - 1);
  wp[(size_t)permn(n) * K + k] = f2e4m3(w[idx] * kScale);
}
__global__ void k_conv_b(const float* __restrict__ b, float* __restrict__ bp) {
  int idx = blockIdx.x * 256 + threadIdx.x;
  if (idx < kNG) bp[permn(idx)] = b[idx];
}
__global__ void k_conv_wout(const float* __restrict__ w, u8* __restrict__ wp) {
  int idx = blockIdx.x * 256 + threadIdx.x;
  if (idx >= 384 * kH) return;
  int n = idx >> 10, k = idx & 1023;
  wp[idx] = (n < kV) ? f2e4m3(w[(size_t)n * kH + k] * kScale) : (u8)0;
}
__global__ void k_conv_emb(const float* __restrict__ e, u8* __restrict__ ep) {
  int idx = blockIdx.x * 256 + threadIdx.x;
  if (idx < kV * kE) ep[idx] = f2e4m3(e[idx] * kScale);
}

extern "C" void kernel_launch(void* const* d_in, const int* in_sizes, int n_in,
                              void* d_out, int out_size, void* d_ws, size_t ws_size,
                              hipStream_t stream)
{
  const int*   target = (const int*)d_in[0];
  const int*   bosp   = (const int*)d_in[1];
  const float* emb    = (const float*)d_in[2];
  const float* w_ih1  = (const float*)d_in[3];
  const float* w_hh1  = (const float*)d_in[4];
  const float* b_ih1  = (const float*)d_in[5];
  const float* b_hh1  = (const float*)d_in[6];
  const float* w_ih2  = (const float*)d_in[7];
  const float* w_hh2  = (const float*)d_in[8];
  const float* b_ih2  = (const float*)d_in[9];
  const float* b_hh2  = (const float*)d_in[10];
  const float* w_ih3  = (const float*)d_in[11];
  const float* w_hh3  = (const float*)d_in[12];
  const float* b_ih3  = (const float*)d_in[13];
  const float* b_hh3  = (const float*)d_in[14];
  const float* w_out  = (const float*)d_in[15];
  const float* b_out  = (const float*)d_in[16];

  char* ws = (char*)d_ws;
  size_t off = 0;
  auto alloc = [&](size_t bytes) -> void* {
    void* p = ws + off;
    off = (off + bytes + 511) & ~(size_t)511;
    return p;
  };
  u8* w1i = (u8*)alloc((size_t)kNG * kE);
  u8* w1h = (u8*)alloc((size_t)kNG * kH);
  u8* w2i = (u8*)alloc((size_t)kNG * kH);
  u8* w2h = (u8*)alloc((size_t)kNG * kH);
  u8* w3i = (u8*)alloc((size_t)kNG * kH);
  u8* w3h = (u8*)alloc((size_t)kNG * kH);
  u8* wo  = (u8*)alloc((size_t)384 * kH);
  u8* eb  = (u8*)alloc((size_t)kV * kE);
  float* bi1 = (float*)alloc(kNG * 4);
  float* bh1 = (float*)alloc(kNG * 4);
  float* bi2 = (float*)alloc(kNG * 4);
  float* bh2 = (float*)alloc(kNG * 4);
  float* bi3 = (float*)alloc(kNG * 4);
  float* bh3 = (float*)alloc(kNG * 4);
  float* h1f = (float*)alloc((size_t)2 * kB * kH * 4);
  float* h2f = (float*)alloc((size_t)2 * kB * kH * 4);
  float* h3f = (float*)alloc((size_t)2 * kB * kH * 4);
  u8* h1b = (u8*)alloc((size_t)2 * kB * kH);
  u8* h2b = (u8*)alloc((size_t)2 * kB * kH);
  u8* h3b = (u8*)alloc((size_t)2 * kB * kH);
  unsigned* bar = (unsigned*)alloc(8192);
  (void)ws_size; (void)in_sizes; (void)n_in; (void)out_size;

  k_conv_w<<<(kNG * kE + 255) / 256, 256, 0, stream>>>(w_ih1, w1i, kE, 9);
  k_conv_w<<<(kNG * kH + 255) / 256, 256, 0, stream>>>(w_hh1, w1h, kH, 10);
  k_conv_w<<<(kNG * kH + 255) / 256, 256, 0, stream>>>(w_ih2, w2i, kH, 10);
  k_conv_w<<<(kNG * kH + 255) / 256, 256, 0, stream>>>(w_hh2, w2h, kH, 10);
  k_conv_w<<<(kNG * kH + 255) / 256, 256, 0, stream>>>(w_ih3, w3i, kH, 10);
  k_conv_w<<<(kNG * kH + 255) / 256, 256, 0, stream>>>(w_hh3, w3h, kH, 10);
  k_conv_b<<<(kNG + 255) / 256, 256, 0, stream>>>(b_ih1, bi1);
  k_conv_b<<<(kNG + 255) / 256, 256, 0, stream>>>(b_hh1, bh1);
  k_conv_b<<<(kNG + 255) / 256, 256, 0, stream>>>(b_ih2, bi2);
  k_conv_b<<<(kNG + 255) / 256, 256, 0, stream>>>(b_hh2, bh2);
  k_conv_b<<<(kNG + 255) / 256, 256, 0, stream>>>(b_ih3, bi3);
  k_conv_b<<<(kNG + 255) / 256, 256, 0, stream>>>(b_hh3, bh3);
  k_conv_wout<<<(384 * kH + 255) / 256, 256, 0, stream>>>(w_out, wo);
  k_conv_emb<<<(kV * kE + 255) / 256, 256, 0, stream>>>(emb, eb);

  hipMemsetAsync(h1f, 0, (size_t)3 * 2 * kB * kH * 4, stream);  // h1f,h2f,h3f contiguous
  hipMemsetAsync(h1b, 0, (size_t)3 * 2 * kB * kH, stream);      // h1b,h2b,h3b contiguous
  hipMemsetAsync(bar, 0, 8192, stream);
  hipMemsetAsync(d_out, 0, (size_t)kB * 4, stream);

  Params P;
  P.target = target; P.bosp = bosp; P.b_out = b_out;
  P.w1i = w1i; P.w1h = w1h; P.w2i = w2i; P.w2h = w2h; P.w3i = w3i; P.w3h = w3h;
  P.wout = wo; P.embb = eb;
  P.bi1 = bi1; P.bh1 = bh1; P.bi2 = bi2; P.bh2 = bh2; P.bi3 = bi3; P.bh3 = bh3;
  P.h1f = h1f; P.h2f = h2f; P.h3f = h3f;
  P.h1b = h1b; P.h2b = h2b; P.h3b = h3b;
  P.lp = (float*)d_out;
  P.acnt = bar; P.gflag = bar + 1024;

  rnn_main<<<dim3(NB), dim3(256), 0, stream>>>(P);
}